// Round 14
// baseline (173.080 us; speedup 1.0000x reference)
//
#include <hip/hip_runtime.h>
#include <hip/hip_bf16.h>

// GCN 2-layer forward on MI355X.  (round-12 structure + 4-pass src-range agg1)
// wt+zero -> fat{phase1-bin ∪ MFMA-GEMM1(unscaled)} -> phase2 (inline bucket
// scan -> rowstart+dinv+csr) -> FUSED agg1(4-pass src-range gather)+relu+GEMM2
// -> agg2 (pre-scaled, f32 out, UNCHANGED control)

#define IN_C 128
#define HID_C 128
#define OUT_C 64
#define BKT_SH 8
#define BKT_NODES 256
#define CHUNK 4096
#define CAPB 6144
#define OVF_CAP 65536

typedef float f32x4 __attribute__((ext_vector_type(4)));
typedef short bf16x8 __attribute__((ext_vector_type(8)));

__device__ inline unsigned short f2bf_rtn(float f) {
  unsigned u = __float_as_uint(f);
  unsigned r = u + 0x7fffu + ((u >> 16) & 1u);
  return (unsigned short)(r >> 16);
}
__device__ inline unsigned pack_bf2(float a, float b) {
  return (unsigned)f2bf_rtn(a) | ((unsigned)f2bf_rtn(b) << 16);
}

// ---- W transpose + bf16 convert + zero atomic counters ----
__global__ __launch_bounds__(256) void wt_zero_kernel(
    const float* __restrict__ W1, const float* __restrict__ W2,
    short* __restrict__ w1t, short* __restrict__ w2t,
    int* __restrict__ zbase, int zints) {
  int i = blockIdx.x * 256 + threadIdx.x;
  if (i < zints) zbase[i] = 0;
  if (i < IN_C * HID_C) {
    int n = i >> 7, k = i & 127;
    w1t[i] = (short)f2bf_rtn(W1[k * HID_C + n]);
  }
  if (i < HID_C * OUT_C) {
    int n = i >> 7, k = i & 127;
    w2t[i] = (short)f2bf_rtn(W2[k * OUT_C + n]);
  }
}

// ---- Fat kernel: blocks [0,P1B) = LDS-binned edge partition;
//      blocks [P1B, P1B+GB) = MFMA GEMM1 (f32 X @ w1t -> bf16 hs, UNscaled).
__global__ __launch_bounds__(256) void p1_gemm1_kernel(
    const int* __restrict__ ei, unsigned* __restrict__ pairs,
    int* __restrict__ bcnt, uint2* __restrict__ ovf, int* __restrict__ ovf_cnt,
    int* __restrict__ ovfb, int E, int K, int P1B,
    const float* __restrict__ X, const short* __restrict__ Wt,
    unsigned short* __restrict__ H, int ntiles) {
  int t = threadIdx.x;
  if ((int)blockIdx.x < P1B) {
    __shared__ unsigned buf[CHUNK];
    __shared__ int hist[256];
    __shared__ int lofs[256];
    __shared__ int cur[256];
    __shared__ int gbase[256];
    __shared__ int ws4[4];
    int base_e = blockIdx.x * CHUNK;
    int cnt_e = E - base_e;
    if (cnt_e > CHUNK) cnt_e = CHUNK;

    hist[t] = 0;
    __syncthreads();

    for (int i = t; i < cnt_e; i += 256)
      atomicAdd(&hist[ei[E + base_e + i] >> BKT_SH], 1);
    __syncthreads();

    int v = hist[t];
    int lane = t & 63, wid = t >> 6;
    int inc = v;
    #pragma unroll
    for (int off = 1; off < 64; off <<= 1) {
      int u = __shfl_up(inc, off, 64);
      if (lane >= off) inc += u;
    }
    if (lane == 63) ws4[wid] = inc;
    __syncthreads();
    if (t == 0) {
      int a = ws4[0], b = ws4[1], c = ws4[2];
      ws4[0] = 0; ws4[1] = a; ws4[2] = a + b; ws4[3] = a + b + c;
    }
    __syncthreads();
    int excl = ws4[wid] + inc - v;
    lofs[t] = excl;
    cur[t] = excl;
    if (t < K && v > 0) gbase[t] = atomicAdd(&bcnt[t], v);
    __syncthreads();

    for (int i = t; i < cnt_e; i += 256) {
      int src = ei[base_e + i];
      int dst = ei[E + base_e + i];
      int b = dst >> BKT_SH;
      int pos = atomicAdd(&cur[b], 1);
      buf[pos] = (unsigned)src | ((unsigned)(dst & (BKT_NODES - 1)) << 16) |
                 ((unsigned)b << 24);
    }
    __syncthreads();

    for (int i = t; i < cnt_e; i += 256) {
      unsigned w = buf[i];
      int b = w >> 24;
      int g = gbase[b] + (i - lofs[b]);
      if (g < CAPB) {
        pairs[(size_t)b * CAPB + g] = w;
      } else {
        int oi = atomicAdd(ovf_cnt, 1);
        if (oi < OVF_CAP) {
          unsigned dst = (unsigned)(b << BKT_SH) | ((w >> 16) & 0xFFu);
          ovf[oi] = make_uint2(w & 0xFFFFu, dst);
          atomicAdd(&ovfb[b], 1);
        }
      }
    }
  } else {
    // ---------- GEMM1: one 16-row tile per wave, no dinv scale ----------
    int lane = t & 63;
    int tile = ((int)blockIdx.x - P1B) * 4 + (t >> 6);
    if (tile >= ntiles) return;
    constexpr int NT = HID_C / 16;

    int arow = tile * 16 + (lane & 15);
    int kch = (lane >> 4) * 8;

    bf16x8 afrag[4];
    const float4* Xf = (const float4*)X;
    #pragma unroll
    for (int kt = 0; kt < 4; ++kt) {
      float4 f0 = Xf[(size_t)arow * 32 + (kt * 32 + kch) / 4];
      float4 f1 = Xf[(size_t)arow * 32 + (kt * 32 + kch) / 4 + 1];
      bf16x8 a;
      a[0] = (short)f2bf_rtn(f0.x); a[1] = (short)f2bf_rtn(f0.y);
      a[2] = (short)f2bf_rtn(f0.z); a[3] = (short)f2bf_rtn(f0.w);
      a[4] = (short)f2bf_rtn(f1.x); a[5] = (short)f2bf_rtn(f1.y);
      a[6] = (short)f2bf_rtn(f1.z); a[7] = (short)f2bf_rtn(f1.w);
      afrag[kt] = a;
    }

    const bf16x8* W8 = (const bf16x8*)Wt;
    f32x4 zero = {0.f, 0.f, 0.f, 0.f};
    f32x4 acc[NT];
    #pragma unroll
    for (int ct = 0; ct < NT; ++ct) acc[ct] = zero;

    #pragma unroll
    for (int ct = 0; ct < NT; ++ct) {
      int bcol = ct * 16 + (lane & 15);
      #pragma unroll
      for (int kt = 0; kt < 4; ++kt) {
        bf16x8 b = W8[bcol * 16 + (kt * 32 + kch) / 8];
        acc[ct] = __builtin_amdgcn_mfma_f32_16x16x32_bf16(afrag[kt], b, acc[ct], 0, 0, 0);
      }
    }

    int r0 = tile * 16 + (lane >> 4) * 4;
    #pragma unroll
    for (int ct = 0; ct < NT; ++ct) {
      #pragma unroll
      for (int j = 0; j < 4; ++j)
        H[(size_t)(r0 + j) * HID_C + ct * 16 + (lane & 15)] = f2bf_rtn(acc[ct][j]);
    }
  }
}

// ---- Phase 2: inline bucket-base scan; per-bucket hist/scan ->
//      rowstart + dinv + csr (uint16) ----
__global__ __launch_bounds__(256) void phase2_csr_kernel(
    const unsigned* __restrict__ pairs, const int* __restrict__ bcnt,
    const int* __restrict__ ovfb, const uint2* __restrict__ ovf,
    const int* __restrict__ ovf_cnt, int* __restrict__ rowstart,
    float* __restrict__ dinv, unsigned short* __restrict__ csr, int N, int K) {
  int b = blockIdx.x;
  int t = threadIdx.x;
  __shared__ int hist[BKT_NODES];
  __shared__ int cur[BKT_NODES];
  __shared__ int sbase[256];
  __shared__ int ws4[4];
  int lane = t & 63, wid = t >> 6;

  int cb = 0;
  if (t < K) {
    int c = bcnt[t];
    cb = (c < CAPB ? c : CAPB) + ovfb[t];
  }
  {
    int inc = cb;
    #pragma unroll
    for (int off = 1; off < 64; off <<= 1) {
      int u = __shfl_up(inc, off, 64);
      if (lane >= off) inc += u;
    }
    if (lane == 63) ws4[wid] = inc;
    __syncthreads();
    if (t == 0) {
      int a = ws4[0], bb = ws4[1], c = ws4[2];
      ws4[0] = 0; ws4[1] = a; ws4[2] = a + bb; ws4[3] = a + bb + c;
    }
    __syncthreads();
    int excl = ws4[wid] + inc - cb;
    sbase[t] = excl;
    if (b == K - 1 && t == K - 1) rowstart[N] = excl + cb;
  }
  __syncthreads();
  int base = sbase[b];

  hist[t] = 0;
  __syncthreads();

  int cnt = bcnt[b];
  if (cnt > CAPB) cnt = CAPB;
  const unsigned* reg = pairs + (size_t)b * CAPB;

  for (int i = t; i < cnt; i += 256)
    atomicAdd(&hist[(reg[i] >> 16) & 0xFFu], 1);
  int oc = *ovf_cnt;
  if (oc > OVF_CAP) oc = OVF_CAP;
  for (int i = t; i < oc; i += 256) {
    uint2 p = ovf[i];
    if ((int)(p.y >> BKT_SH) == b) atomicAdd(&hist[p.y & (BKT_NODES - 1)], 1);
  }
  __syncthreads();

  int v = hist[t];
  int inc = v;
  #pragma unroll
  for (int off = 1; off < 64; off <<= 1) {
    int u = __shfl_up(inc, off, 64);
    if (lane >= off) inc += u;
  }
  __syncthreads();
  if (lane == 63) ws4[wid] = inc;
  __syncthreads();
  if (t == 0) {
    int a = ws4[0], bb = ws4[1], c = ws4[2];
    ws4[0] = 0; ws4[1] = a; ws4[2] = a + bb; ws4[3] = a + bb + c;
  }
  __syncthreads();
  int excl = ws4[wid] + inc - v;

  int node = b * BKT_NODES + t;
  if (node < N) {
    rowstart[node] = base + excl;
    dinv[node] = rsqrtf((float)(v + 1));
  }
  cur[t] = base + excl;
  __syncthreads();

  for (int i = t; i < cnt; i += 256) {
    unsigned w = reg[i];
    int pos = atomicAdd(&cur[(w >> 16) & 0xFFu], 1);
    csr[pos] = (unsigned short)(w & 0xffffu);
  }
  for (int i = t; i < oc; i += 256) {
    uint2 p = ovf[i];
    if ((int)(p.y >> BKT_SH) == b) {
      int pos = atomicAdd(&cur[p.y & (BKT_NODES - 1)], 1);
      csr[pos] = (unsigned short)p.x;
    }
  }
}

// ---- FUSED: agg1 (4-pass src-range gather, dinv[src]-scaled, +b1, relu)
//      -> LDS tile -> MFMA GEMM2 (x2tile @ w2t) * dinv[row] -> hs2 (bf16).
// Block = 256 threads = 16 nodes x 16 lanes. 4 src-range passes keep the
// active hs slice (~3.2MB) XCD-L2-resident via temporal phase alignment.
__global__ __launch_bounds__(256) void agg1_gemm2_kernel(
    const unsigned short* __restrict__ Hs, const int* __restrict__ rowstart,
    const unsigned short* __restrict__ csr, const float* __restrict__ dinv,
    const float* __restrict__ b1, const short* __restrict__ w2t,
    unsigned short* __restrict__ H2, int n) {
  __shared__ unsigned x2s[16][64];  // 16 rows x 128 bf16 = 4KB
  int t = threadIdx.x;
  int row = t >> 4;
  int lane16 = t & 15;
  int node = blockIdx.x * 16 + row;

  float acc[8];
  #pragma unroll
  for (int j = 0; j < 8; ++j) acc[j] = 0.f;

  if (node < n) {
    const uint4* H4 = reinterpret_cast<const uint4*>(Hs);
    int s = rowstart[node];
    int e = rowstart[node + 1];
    float dnode = dinv[node];

    {
      uint4 v = H4[(size_t)node * 16 + lane16];  // self-loop
      acc[0] = __uint_as_float(v.x << 16) * dnode;
      acc[1] = __uint_as_float(v.x & 0xffff0000u) * dnode;
      acc[2] = __uint_as_float(v.y << 16) * dnode;
      acc[3] = __uint_as_float(v.y & 0xffff0000u) * dnode;
      acc[4] = __uint_as_float(v.z << 16) * dnode;
      acc[5] = __uint_as_float(v.z & 0xffff0000u) * dnode;
      acc[6] = __uint_as_float(v.w << 16) * dnode;
      acc[7] = __uint_as_float(v.w & 0xffff0000u) * dnode;
    }

    int passN = (n + 3) >> 2;
    for (int pass = 0; pass < 4; ++pass) {
      int lo = pass * passN;
      int hi = lo + passN;
      for (int p = s; p < e; ++p) {
        int s0 = csr[p];
        if (s0 < lo || s0 >= hi) continue;
        float d0 = dinv[s0];
        uint4 v0 = H4[(size_t)s0 * 16 + lane16];
        acc[0] = fmaf(__uint_as_float(v0.x << 16), d0, acc[0]);
        acc[1] = fmaf(__uint_as_float(v0.x & 0xffff0000u), d0, acc[1]);
        acc[2] = fmaf(__uint_as_float(v0.y << 16), d0, acc[2]);
        acc[3] = fmaf(__uint_as_float(v0.y & 0xffff0000u), d0, acc[3]);
        acc[4] = fmaf(__uint_as_float(v0.z << 16), d0, acc[4]);
        acc[5] = fmaf(__uint_as_float(v0.z & 0xffff0000u), d0, acc[5]);
        acc[6] = fmaf(__uint_as_float(v0.w << 16), d0, acc[6]);
        acc[7] = fmaf(__uint_as_float(v0.w & 0xffff0000u), d0, acc[7]);
      }
    }

    float dnode2 = dnode;
    const float4* b4 = reinterpret_cast<const float4*>(b1);
    float4 bv0 = b4[lane16 * 2];
    float4 bv1 = b4[lane16 * 2 + 1];
    acc[0] = fmaxf(fmaf(acc[0], dnode2, bv0.x), 0.f);
    acc[1] = fmaxf(fmaf(acc[1], dnode2, bv0.y), 0.f);
    acc[2] = fmaxf(fmaf(acc[2], dnode2, bv0.z), 0.f);
    acc[3] = fmaxf(fmaf(acc[3], dnode2, bv0.w), 0.f);
    acc[4] = fmaxf(fmaf(acc[4], dnode2, bv1.x), 0.f);
    acc[5] = fmaxf(fmaf(acc[5], dnode2, bv1.y), 0.f);
    acc[6] = fmaxf(fmaf(acc[6], dnode2, bv1.z), 0.f);
    acc[7] = fmaxf(fmaf(acc[7], dnode2, bv1.w), 0.f);
  }

  // pack x2 row to LDS (bf16)
  x2s[row][lane16 * 4 + 0] = pack_bf2(acc[0], acc[1]);
  x2s[row][lane16 * 4 + 1] = pack_bf2(acc[2], acc[3]);
  x2s[row][lane16 * 4 + 2] = pack_bf2(acc[4], acc[5]);
  x2s[row][lane16 * 4 + 3] = pack_bf2(acc[6], acc[7]);
  __syncthreads();

  // GEMM2: wave w computes 16-col slice ct=w of the 16x64 output tile.
  int lane = t & 63;
  int w = t >> 6;
  int kch = (lane >> 4) * 8;

  const bf16x8* W8 = (const bf16x8*)w2t;
  f32x4 oacc = {0.f, 0.f, 0.f, 0.f};
  int bcol = w * 16 + (lane & 15);
  #pragma unroll
  for (int kt = 0; kt < 4; ++kt) {
    bf16x8 a = *reinterpret_cast<const bf16x8*>(&x2s[lane & 15][kt * 16 + kch / 2]);
    bf16x8 b = W8[bcol * 16 + (kt * 32 + kch) / 8];
    oacc = __builtin_amdgcn_mfma_f32_16x16x32_bf16(a, b, oacc, 0, 0, 0);
  }

  int r0 = (lane >> 4) * 4;
  #pragma unroll
  for (int j = 0; j < 4; ++j) {
    int g = blockIdx.x * 16 + r0 + j;
    if (g < n)
      H2[(size_t)g * OUT_C + w * 16 + (lane & 15)] = f2bf_rtn(oacc[j] * dinv[g]);
  }
}

// ---- agg2 (UNCHANGED control): out = dinv*(hs2[node]+sum hs2[src]) + b2 ----
__global__ __launch_bounds__(256) void agg2_kernel(
    const unsigned short* __restrict__ Hs, const int* __restrict__ rowstart,
    const unsigned short* __restrict__ csr, const float* __restrict__ dinv,
    const float* __restrict__ bias, float* __restrict__ out, int n) {
  constexpr int TPN = OUT_C / 8;   // 8
  constexpr int NPB = 256 / TPN;   // 32
  int lane = threadIdx.x % TPN;
  int node = blockIdx.x * NPB + threadIdx.x / TPN;
  if (node >= n) return;

  const uint4* H4 = reinterpret_cast<const uint4*>(Hs);
  int s = rowstart[node];
  int e = rowstart[node + 1];

  float acc[8];
  {
    uint4 v = H4[(size_t)node * TPN + lane];
    acc[0] = __uint_as_float(v.x << 16);
    acc[1] = __uint_as_float(v.x & 0xffff0000u);
    acc[2] = __uint_as_float(v.y << 16);
    acc[3] = __uint_as_float(v.y & 0xffff0000u);
    acc[4] = __uint_as_float(v.z << 16);
    acc[5] = __uint_as_float(v.z & 0xffff0000u);
    acc[6] = __uint_as_float(v.w << 16);
    acc[7] = __uint_as_float(v.w & 0xffff0000u);
  }

  int p = s;
  for (; p + 1 < e; p += 2) {
    int s0 = csr[p];
    int s1 = csr[p + 1];
    uint4 v0 = H4[(size_t)s0 * TPN + lane];
    uint4 v1 = H4[(size_t)s1 * TPN + lane];
    acc[0] += __uint_as_float(v0.x << 16);
    acc[1] += __uint_as_float(v0.x & 0xffff0000u);
    acc[2] += __uint_as_float(v0.y << 16);
    acc[3] += __uint_as_float(v0.y & 0xffff0000u);
    acc[4] += __uint_as_float(v0.z << 16);
    acc[5] += __uint_as_float(v0.z & 0xffff0000u);
    acc[6] += __uint_as_float(v0.w << 16);
    acc[7] += __uint_as_float(v0.w & 0xffff0000u);
    acc[0] += __uint_as_float(v1.x << 16);
    acc[1] += __uint_as_float(v1.x & 0xffff0000u);
    acc[2] += __uint_as_float(v1.y << 16);
    acc[3] += __uint_as_float(v1.y & 0xffff0000u);
    acc[4] += __uint_as_float(v1.z << 16);
    acc[5] += __uint_as_float(v1.z & 0xffff0000u);
    acc[6] += __uint_as_float(v1.w << 16);
    acc[7] += __uint_as_float(v1.w & 0xffff0000u);
  }
  if (p < e) {
    int s0 = csr[p];
    uint4 v0 = H4[(size_t)s0 * TPN + lane];
    acc[0] += __uint_as_float(v0.x << 16);
    acc[1] += __uint_as_float(v0.x & 0xffff0000u);
    acc[2] += __uint_as_float(v0.y << 16);
    acc[3] += __uint_as_float(v0.y & 0xffff0000u);
    acc[4] += __uint_as_float(v0.z << 16);
    acc[5] += __uint_as_float(v0.z & 0xffff0000u);
    acc[6] += __uint_as_float(v0.w << 16);
    acc[7] += __uint_as_float(v0.w & 0xffff0000u);
  }

  float dnode = dinv[node];
  float4 b0 = reinterpret_cast<const float4*>(bias)[lane * 2];
  float4 b1 = reinterpret_cast<const float4*>(bias)[lane * 2 + 1];
  float4* o4 = reinterpret_cast<float4*>(out) + (size_t)node * (OUT_C / 4);
  o4[lane * 2] = make_float4(fmaf(acc[0], dnode, b0.x), fmaf(acc[1], dnode, b0.y),
                             fmaf(acc[2], dnode, b0.z), fmaf(acc[3], dnode, b0.w));
  o4[lane * 2 + 1] = make_float4(fmaf(acc[4], dnode, b1.x), fmaf(acc[5], dnode, b1.y),
                                 fmaf(acc[6], dnode, b1.z), fmaf(acc[7], dnode, b1.w));
}

extern "C" void kernel_launch(void* const* d_in, const int* in_sizes, int n_in,
                              void* d_out, int out_size, void* d_ws, size_t ws_size,
                              hipStream_t stream) {
  const float* x  = (const float*)d_in[0];
  const int*   ei = (const int*)d_in[1];
  const float* W1 = (const float*)d_in[2];
  const float* b1 = (const float*)d_in[3];
  const float* W2 = (const float*)d_in[4];
  const float* b2 = (const float*)d_in[5];
  float* out = (float*)d_out;

  const int N = in_sizes[0] / IN_C;             // 50000
  const int E = in_sizes[1] / 2;                // 800000
  const int K = (N + BKT_NODES - 1) >> BKT_SH;  // 196 buckets
  const int NTILES = (N + 15) / 16;             // 3125
  const int P1B = (E + CHUNK - 1) / CHUNK;      // 196
  const int GB1 = (NTILES + 3) / 4;             // 782

  char* ws = (char*)d_ws;
  size_t off = 0;
  auto alloc = [&](size_t bytes) -> void* {
    void* p = ws + off;
    off += (bytes + 255) & ~(size_t)255;
    return p;
  };
  int* bcnt    = (int*)alloc((size_t)K * 4);
  int* ovf_cnt = (int*)alloc(4);
  int* ovfb    = (int*)alloc((size_t)K * 4);
  size_t zero_bytes = off;
  const int zints = (int)(zero_bytes / 4);

  int*   rowstart    = (int*)  alloc((size_t)(N + 1) * 4);
  float* dinv        = (float*)alloc((size_t)N * 4);
  unsigned* pairs    = (unsigned*)alloc((size_t)K * CAPB * 4);
  uint2* ovf         = (uint2*)alloc((size_t)OVF_CAP * 8);
  unsigned short* csr = (unsigned short*)alloc((size_t)E * 2);
  unsigned short* hs  = (unsigned short*)alloc((size_t)N * HID_C * 2);
  unsigned short* hs2 = (unsigned short*)alloc((size_t)N * OUT_C * 2);
  short* w1t         = (short*)alloc((size_t)IN_C * HID_C * 2);
  short* w2t         = (short*)alloc((size_t)HID_C * OUT_C * 2);

  int wt_threads = zints > IN_C * HID_C ? zints : IN_C * HID_C;
  wt_zero_kernel<<<(wt_threads + 255) / 256, 256, 0, stream>>>(
      W1, W2, w1t, w2t, (int*)ws, zints);

  p1_gemm1_kernel<<<P1B + GB1, 256, 0, stream>>>(
      ei, pairs, bcnt, ovf, ovf_cnt, ovfb, E, K, P1B, x, w1t, hs, NTILES);

  phase2_csr_kernel<<<K, 256, 0, stream>>>(
      pairs, bcnt, ovfb, ovf, ovf_cnt, rowstart, dinv, csr, N, K);

  agg1_gemm2_kernel<<<NTILES, 256, 0, stream>>>(
      hs, rowstart, csr, dinv, b1, w2t, hs2, N);

  agg2_kernel<<<(N + 31) / 32, 256, 0, stream>>>(
      hs2, rowstart, csr, dinv, b2, out, N);
}

// Round 15
// 102.881 us; speedup vs baseline: 1.6823x; 1.6823x over previous
//
#include <hip/hip_runtime.h>
#include <hip/hip_bf16.h>

// GCN 2-layer forward on MI355X.  (round-12 best-known configuration)
// wt+zero -> fat{phase1-bin ∪ MFMA-GEMM1(unscaled)} -> phase2 (inline bucket
// scan -> rowstart+dinv+csr) -> FUSED agg1(dinv[src]-scaled)+relu+GEMM2(*dinv)
// -> agg2 (pre-scaled, f32 out)

#define IN_C 128
#define HID_C 128
#define OUT_C 64
#define BKT_SH 8
#define BKT_NODES 256
#define CHUNK 4096
#define CAPB 6144
#define OVF_CAP 65536

typedef float f32x4 __attribute__((ext_vector_type(4)));
typedef short bf16x8 __attribute__((ext_vector_type(8)));

__device__ inline unsigned short f2bf_rtn(float f) {
  unsigned u = __float_as_uint(f);
  unsigned r = u + 0x7fffu + ((u >> 16) & 1u);
  return (unsigned short)(r >> 16);
}
__device__ inline unsigned pack_bf2(float a, float b) {
  return (unsigned)f2bf_rtn(a) | ((unsigned)f2bf_rtn(b) << 16);
}

// ---- W transpose + bf16 convert + zero atomic counters ----
__global__ __launch_bounds__(256) void wt_zero_kernel(
    const float* __restrict__ W1, const float* __restrict__ W2,
    short* __restrict__ w1t, short* __restrict__ w2t,
    int* __restrict__ zbase, int zints) {
  int i = blockIdx.x * 256 + threadIdx.x;
  if (i < zints) zbase[i] = 0;
  if (i < IN_C * HID_C) {
    int n = i >> 7, k = i & 127;
    w1t[i] = (short)f2bf_rtn(W1[k * HID_C + n]);
  }
  if (i < HID_C * OUT_C) {
    int n = i >> 7, k = i & 127;
    w2t[i] = (short)f2bf_rtn(W2[k * OUT_C + n]);
  }
}

// ---- Fat kernel: blocks [0,P1B) = LDS-binned edge partition;
//      blocks [P1B, P1B+GB) = MFMA GEMM1 (f32 X @ w1t -> bf16 hs, UNscaled).
__global__ __launch_bounds__(256) void p1_gemm1_kernel(
    const int* __restrict__ ei, unsigned* __restrict__ pairs,
    int* __restrict__ bcnt, uint2* __restrict__ ovf, int* __restrict__ ovf_cnt,
    int* __restrict__ ovfb, int E, int K, int P1B,
    const float* __restrict__ X, const short* __restrict__ Wt,
    unsigned short* __restrict__ H, int ntiles) {
  int t = threadIdx.x;
  if ((int)blockIdx.x < P1B) {
    __shared__ unsigned buf[CHUNK];
    __shared__ int hist[256];
    __shared__ int lofs[256];
    __shared__ int cur[256];
    __shared__ int gbase[256];
    __shared__ int ws4[4];
    int base_e = blockIdx.x * CHUNK;
    int cnt_e = E - base_e;
    if (cnt_e > CHUNK) cnt_e = CHUNK;

    hist[t] = 0;
    __syncthreads();

    for (int i = t; i < cnt_e; i += 256)
      atomicAdd(&hist[ei[E + base_e + i] >> BKT_SH], 1);
    __syncthreads();

    int v = hist[t];
    int lane = t & 63, wid = t >> 6;
    int inc = v;
    #pragma unroll
    for (int off = 1; off < 64; off <<= 1) {
      int u = __shfl_up(inc, off, 64);
      if (lane >= off) inc += u;
    }
    if (lane == 63) ws4[wid] = inc;
    __syncthreads();
    if (t == 0) {
      int a = ws4[0], b = ws4[1], c = ws4[2];
      ws4[0] = 0; ws4[1] = a; ws4[2] = a + b; ws4[3] = a + b + c;
    }
    __syncthreads();
    int excl = ws4[wid] + inc - v;
    lofs[t] = excl;
    cur[t] = excl;
    if (t < K && v > 0) gbase[t] = atomicAdd(&bcnt[t], v);
    __syncthreads();

    for (int i = t; i < cnt_e; i += 256) {
      int src = ei[base_e + i];
      int dst = ei[E + base_e + i];
      int b = dst >> BKT_SH;
      int pos = atomicAdd(&cur[b], 1);
      buf[pos] = (unsigned)src | ((unsigned)(dst & (BKT_NODES - 1)) << 16) |
                 ((unsigned)b << 24);
    }
    __syncthreads();

    for (int i = t; i < cnt_e; i += 256) {
      unsigned w = buf[i];
      int b = w >> 24;
      int g = gbase[b] + (i - lofs[b]);
      if (g < CAPB) {
        pairs[(size_t)b * CAPB + g] = w;
      } else {
        int oi = atomicAdd(ovf_cnt, 1);
        if (oi < OVF_CAP) {
          unsigned dst = (unsigned)(b << BKT_SH) | ((w >> 16) & 0xFFu);
          ovf[oi] = make_uint2(w & 0xFFFFu, dst);
          atomicAdd(&ovfb[b], 1);
        }
      }
    }
  } else {
    // ---------- GEMM1: one 16-row tile per wave, no dinv scale ----------
    int lane = t & 63;
    int tile = ((int)blockIdx.x - P1B) * 4 + (t >> 6);
    if (tile >= ntiles) return;
    constexpr int NT = HID_C / 16;

    int arow = tile * 16 + (lane & 15);
    int kch = (lane >> 4) * 8;

    bf16x8 afrag[4];
    const float4* Xf = (const float4*)X;
    #pragma unroll
    for (int kt = 0; kt < 4; ++kt) {
      float4 f0 = Xf[(size_t)arow * 32 + (kt * 32 + kch) / 4];
      float4 f1 = Xf[(size_t)arow * 32 + (kt * 32 + kch) / 4 + 1];
      bf16x8 a;
      a[0] = (short)f2bf_rtn(f0.x); a[1] = (short)f2bf_rtn(f0.y);
      a[2] = (short)f2bf_rtn(f0.z); a[3] = (short)f2bf_rtn(f0.w);
      a[4] = (short)f2bf_rtn(f1.x); a[5] = (short)f2bf_rtn(f1.y);
      a[6] = (short)f2bf_rtn(f1.z); a[7] = (short)f2bf_rtn(f1.w);
      afrag[kt] = a;
    }

    const bf16x8* W8 = (const bf16x8*)Wt;
    f32x4 zero = {0.f, 0.f, 0.f, 0.f};
    f32x4 acc[NT];
    #pragma unroll
    for (int ct = 0; ct < NT; ++ct) acc[ct] = zero;

    #pragma unroll
    for (int ct = 0; ct < NT; ++ct) {
      int bcol = ct * 16 + (lane & 15);
      #pragma unroll
      for (int kt = 0; kt < 4; ++kt) {
        bf16x8 b = W8[bcol * 16 + (kt * 32 + kch) / 8];
        acc[ct] = __builtin_amdgcn_mfma_f32_16x16x32_bf16(afrag[kt], b, acc[ct], 0, 0, 0);
      }
    }

    int r0 = tile * 16 + (lane >> 4) * 4;
    #pragma unroll
    for (int ct = 0; ct < NT; ++ct) {
      #pragma unroll
      for (int j = 0; j < 4; ++j)
        H[(size_t)(r0 + j) * HID_C + ct * 16 + (lane & 15)] = f2bf_rtn(acc[ct][j]);
    }
  }
}

// ---- Phase 2: inline bucket-base scan; per-bucket hist/scan ->
//      rowstart + dinv + csr (uint16) ----
__global__ __launch_bounds__(256) void phase2_csr_kernel(
    const unsigned* __restrict__ pairs, const int* __restrict__ bcnt,
    const int* __restrict__ ovfb, const uint2* __restrict__ ovf,
    const int* __restrict__ ovf_cnt, int* __restrict__ rowstart,
    float* __restrict__ dinv, unsigned short* __restrict__ csr, int N, int K) {
  int b = blockIdx.x;
  int t = threadIdx.x;
  __shared__ int hist[BKT_NODES];
  __shared__ int cur[BKT_NODES];
  __shared__ int sbase[256];
  __shared__ int ws4[4];
  int lane = t & 63, wid = t >> 6;

  int cb = 0;
  if (t < K) {
    int c = bcnt[t];
    cb = (c < CAPB ? c : CAPB) + ovfb[t];
  }
  {
    int inc = cb;
    #pragma unroll
    for (int off = 1; off < 64; off <<= 1) {
      int u = __shfl_up(inc, off, 64);
      if (lane >= off) inc += u;
    }
    if (lane == 63) ws4[wid] = inc;
    __syncthreads();
    if (t == 0) {
      int a = ws4[0], bb = ws4[1], c = ws4[2];
      ws4[0] = 0; ws4[1] = a; ws4[2] = a + bb; ws4[3] = a + bb + c;
    }
    __syncthreads();
    int excl = ws4[wid] + inc - cb;
    sbase[t] = excl;
    if (b == K - 1 && t == K - 1) rowstart[N] = excl + cb;
  }
  __syncthreads();
  int base = sbase[b];

  hist[t] = 0;
  __syncthreads();

  int cnt = bcnt[b];
  if (cnt > CAPB) cnt = CAPB;
  const unsigned* reg = pairs + (size_t)b * CAPB;

  for (int i = t; i < cnt; i += 256)
    atomicAdd(&hist[(reg[i] >> 16) & 0xFFu], 1);
  int oc = *ovf_cnt;
  if (oc > OVF_CAP) oc = OVF_CAP;
  for (int i = t; i < oc; i += 256) {
    uint2 p = ovf[i];
    if ((int)(p.y >> BKT_SH) == b) atomicAdd(&hist[p.y & (BKT_NODES - 1)], 1);
  }
  __syncthreads();

  int v = hist[t];
  int inc = v;
  #pragma unroll
  for (int off = 1; off < 64; off <<= 1) {
    int u = __shfl_up(inc, off, 64);
    if (lane >= off) inc += u;
  }
  __syncthreads();
  if (lane == 63) ws4[wid] = inc;
  __syncthreads();
  if (t == 0) {
    int a = ws4[0], bb = ws4[1], c = ws4[2];
    ws4[0] = 0; ws4[1] = a; ws4[2] = a + bb; ws4[3] = a + bb + c;
  }
  __syncthreads();
  int excl = ws4[wid] + inc - v;

  int node = b * BKT_NODES + t;
  if (node < N) {
    rowstart[node] = base + excl;
    dinv[node] = rsqrtf((float)(v + 1));
  }
  cur[t] = base + excl;
  __syncthreads();

  for (int i = t; i < cnt; i += 256) {
    unsigned w = reg[i];
    int pos = atomicAdd(&cur[(w >> 16) & 0xFFu], 1);
    csr[pos] = (unsigned short)(w & 0xffffu);
  }
  for (int i = t; i < oc; i += 256) {
    uint2 p = ovf[i];
    if ((int)(p.y >> BKT_SH) == b) {
      int pos = atomicAdd(&cur[p.y & (BKT_NODES - 1)], 1);
      csr[pos] = (unsigned short)p.x;
    }
  }
}

// ---- FUSED: agg1 (dinv[src]-scaled gather over hs, +b1, relu) -> LDS tile
//      -> MFMA GEMM2 (x2tile @ w2t) * dinv[row] -> hs2 (bf16).
// Block = 256 threads = 16 nodes x 16 lanes. x2 never touches global.
__global__ __launch_bounds__(256) void agg1_gemm2_kernel(
    const unsigned short* __restrict__ Hs, const int* __restrict__ rowstart,
    const unsigned short* __restrict__ csr, const float* __restrict__ dinv,
    const float* __restrict__ b1, const short* __restrict__ w2t,
    unsigned short* __restrict__ H2, int n) {
  __shared__ unsigned x2s[16][64];  // 16 rows x 128 bf16 (as 64 u32) = 4KB
  int t = threadIdx.x;
  int row = t >> 4;          // 0..15
  int lane16 = t & 15;       // channel group
  int node = blockIdx.x * 16 + row;

  float acc[8];
  #pragma unroll
  for (int j = 0; j < 8; ++j) acc[j] = 0.f;

  if (node < n) {
    const uint4* H4 = reinterpret_cast<const uint4*>(Hs);
    int s = rowstart[node];
    int e = rowstart[node + 1];
    float dnode = dinv[node];

    {
      uint4 v = H4[(size_t)node * 16 + lane16];  // self-loop
      acc[0] = __uint_as_float(v.x << 16) * dnode;
      acc[1] = __uint_as_float(v.x & 0xffff0000u) * dnode;
      acc[2] = __uint_as_float(v.y << 16) * dnode;
      acc[3] = __uint_as_float(v.y & 0xffff0000u) * dnode;
      acc[4] = __uint_as_float(v.z << 16) * dnode;
      acc[5] = __uint_as_float(v.z & 0xffff0000u) * dnode;
      acc[6] = __uint_as_float(v.w << 16) * dnode;
      acc[7] = __uint_as_float(v.w & 0xffff0000u) * dnode;
    }

    int p = s;
    for (; p + 1 < e; p += 2) {
      int s0 = csr[p];
      int s1 = csr[p + 1];
      uint4 v0 = H4[(size_t)s0 * 16 + lane16];
      uint4 v1 = H4[(size_t)s1 * 16 + lane16];
      float d0 = dinv[s0], d1 = dinv[s1];
      acc[0] = fmaf(__uint_as_float(v0.x << 16), d0, acc[0]);
      acc[1] = fmaf(__uint_as_float(v0.x & 0xffff0000u), d0, acc[1]);
      acc[2] = fmaf(__uint_as_float(v0.y << 16), d0, acc[2]);
      acc[3] = fmaf(__uint_as_float(v0.y & 0xffff0000u), d0, acc[3]);
      acc[4] = fmaf(__uint_as_float(v0.z << 16), d0, acc[4]);
      acc[5] = fmaf(__uint_as_float(v0.z & 0xffff0000u), d0, acc[5]);
      acc[6] = fmaf(__uint_as_float(v0.w << 16), d0, acc[6]);
      acc[7] = fmaf(__uint_as_float(v0.w & 0xffff0000u), d0, acc[7]);
      acc[0] = fmaf(__uint_as_float(v1.x << 16), d1, acc[0]);
      acc[1] = fmaf(__uint_as_float(v1.x & 0xffff0000u), d1, acc[1]);
      acc[2] = fmaf(__uint_as_float(v1.y << 16), d1, acc[2]);
      acc[3] = fmaf(__uint_as_float(v1.y & 0xffff0000u), d1, acc[3]);
      acc[4] = fmaf(__uint_as_float(v1.z << 16), d1, acc[4]);
      acc[5] = fmaf(__uint_as_float(v1.z & 0xffff0000u), d1, acc[5]);
      acc[6] = fmaf(__uint_as_float(v1.w << 16), d1, acc[6]);
      acc[7] = fmaf(__uint_as_float(v1.w & 0xffff0000u), d1, acc[7]);
    }
    if (p < e) {
      int s0 = csr[p];
      uint4 v0 = H4[(size_t)s0 * 16 + lane16];
      float d0 = dinv[s0];
      acc[0] = fmaf(__uint_as_float(v0.x << 16), d0, acc[0]);
      acc[1] = fmaf(__uint_as_float(v0.x & 0xffff0000u), d0, acc[1]);
      acc[2] = fmaf(__uint_as_float(v0.y << 16), d0, acc[2]);
      acc[3] = fmaf(__uint_as_float(v0.y & 0xffff0000u), d0, acc[3]);
      acc[4] = fmaf(__uint_as_float(v0.z << 16), d0, acc[4]);
      acc[5] = fmaf(__uint_as_float(v0.z & 0xffff0000u), d0, acc[5]);
      acc[6] = fmaf(__uint_as_float(v0.w << 16), d0, acc[6]);
      acc[7] = fmaf(__uint_as_float(v0.w & 0xffff0000u), d0, acc[7]);
    }

    float dnode2 = dnode;
    const float4* b4 = reinterpret_cast<const float4*>(b1);
    float4 bv0 = b4[lane16 * 2];
    float4 bv1 = b4[lane16 * 2 + 1];
    acc[0] = fmaxf(fmaf(acc[0], dnode2, bv0.x), 0.f);
    acc[1] = fmaxf(fmaf(acc[1], dnode2, bv0.y), 0.f);
    acc[2] = fmaxf(fmaf(acc[2], dnode2, bv0.z), 0.f);
    acc[3] = fmaxf(fmaf(acc[3], dnode2, bv0.w), 0.f);
    acc[4] = fmaxf(fmaf(acc[4], dnode2, bv1.x), 0.f);
    acc[5] = fmaxf(fmaf(acc[5], dnode2, bv1.y), 0.f);
    acc[6] = fmaxf(fmaf(acc[6], dnode2, bv1.z), 0.f);
    acc[7] = fmaxf(fmaf(acc[7], dnode2, bv1.w), 0.f);
  }

  // pack x2 row to LDS (bf16)
  x2s[row][lane16 * 4 + 0] = pack_bf2(acc[0], acc[1]);
  x2s[row][lane16 * 4 + 1] = pack_bf2(acc[2], acc[3]);
  x2s[row][lane16 * 4 + 2] = pack_bf2(acc[4], acc[5]);
  x2s[row][lane16 * 4 + 3] = pack_bf2(acc[6], acc[7]);
  __syncthreads();

  // GEMM2: wave w computes 16-col slice ct=w of the 16x64 output tile.
  int lane = t & 63;
  int w = t >> 6;
  int kch = (lane >> 4) * 8;   // bf16 offset within 32-k chunk

  const bf16x8* W8 = (const bf16x8*)w2t;
  f32x4 oacc = {0.f, 0.f, 0.f, 0.f};
  int bcol = w * 16 + (lane & 15);
  #pragma unroll
  for (int kt = 0; kt < 4; ++kt) {
    bf16x8 a = *reinterpret_cast<const bf16x8*>(&x2s[lane & 15][kt * 16 + kch / 2]);
    bf16x8 b = W8[bcol * 16 + (kt * 32 + kch) / 8];
    oacc = __builtin_amdgcn_mfma_f32_16x16x32_bf16(a, b, oacc, 0, 0, 0);
  }

  int r0 = (lane >> 4) * 4;
  #pragma unroll
  for (int j = 0; j < 4; ++j) {
    int g = blockIdx.x * 16 + r0 + j;
    if (g < n)
      H2[(size_t)g * OUT_C + w * 16 + (lane & 15)] = f2bf_rtn(oacc[j] * dinv[g]);
  }
}

// ---- agg2: out[node,:] = dinv[node]*(hs2[node,:]+sum hs2[src,:]) + b2 ----
__global__ __launch_bounds__(256) void agg2_kernel(
    const unsigned short* __restrict__ Hs, const int* __restrict__ rowstart,
    const unsigned short* __restrict__ csr, const float* __restrict__ dinv,
    const float* __restrict__ bias, float* __restrict__ out, int n) {
  constexpr int TPN = OUT_C / 8;   // 8
  constexpr int NPB = 256 / TPN;   // 32
  int lane = threadIdx.x % TPN;
  int node = blockIdx.x * NPB + threadIdx.x / TPN;
  if (node >= n) return;

  const uint4* H4 = reinterpret_cast<const uint4*>(Hs);
  int s = rowstart[node];
  int e = rowstart[node + 1];

  float acc[8];
  {
    uint4 v = H4[(size_t)node * TPN + lane];
    acc[0] = __uint_as_float(v.x << 16);
    acc[1] = __uint_as_float(v.x & 0xffff0000u);
    acc[2] = __uint_as_float(v.y << 16);
    acc[3] = __uint_as_float(v.y & 0xffff0000u);
    acc[4] = __uint_as_float(v.z << 16);
    acc[5] = __uint_as_float(v.z & 0xffff0000u);
    acc[6] = __uint_as_float(v.w << 16);
    acc[7] = __uint_as_float(v.w & 0xffff0000u);
  }

  int p = s;
  for (; p + 1 < e; p += 2) {
    int s0 = csr[p];
    int s1 = csr[p + 1];
    uint4 v0 = H4[(size_t)s0 * TPN + lane];
    uint4 v1 = H4[(size_t)s1 * TPN + lane];
    acc[0] += __uint_as_float(v0.x << 16);
    acc[1] += __uint_as_float(v0.x & 0xffff0000u);
    acc[2] += __uint_as_float(v0.y << 16);
    acc[3] += __uint_as_float(v0.y & 0xffff0000u);
    acc[4] += __uint_as_float(v0.z << 16);
    acc[5] += __uint_as_float(v0.z & 0xffff0000u);
    acc[6] += __uint_as_float(v0.w << 16);
    acc[7] += __uint_as_float(v0.w & 0xffff0000u);
    acc[0] += __uint_as_float(v1.x << 16);
    acc[1] += __uint_as_float(v1.x & 0xffff0000u);
    acc[2] += __uint_as_float(v1.y << 16);
    acc[3] += __uint_as_float(v1.y & 0xffff0000u);
    acc[4] += __uint_as_float(v1.z << 16);
    acc[5] += __uint_as_float(v1.z & 0xffff0000u);
    acc[6] += __uint_as_float(v1.w << 16);
    acc[7] += __uint_as_float(v1.w & 0xffff0000u);
  }
  if (p < e) {
    int s0 = csr[p];
    uint4 v0 = H4[(size_t)s0 * TPN + lane];
    acc[0] += __uint_as_float(v0.x << 16);
    acc[1] += __uint_as_float(v0.x & 0xffff0000u);
    acc[2] += __uint_as_float(v0.y << 16);
    acc[3] += __uint_as_float(v0.y & 0xffff0000u);
    acc[4] += __uint_as_float(v0.z << 16);
    acc[5] += __uint_as_float(v0.z & 0xffff0000u);
    acc[6] += __uint_as_float(v0.w << 16);
    acc[7] += __uint_as_float(v0.w & 0xffff0000u);
  }

  float dnode = dinv[node];
  float4 b0 = reinterpret_cast<const float4*>(bias)[lane * 2];
  float4 b1 = reinterpret_cast<const float4*>(bias)[lane * 2 + 1];
  float4* o4 = reinterpret_cast<float4*>(out) + (size_t)node * (OUT_C / 4);
  o4[lane * 2] = make_float4(fmaf(acc[0], dnode, b0.x), fmaf(acc[1], dnode, b0.y),
                             fmaf(acc[2], dnode, b0.z), fmaf(acc[3], dnode, b0.w));
  o4[lane * 2 + 1] = make_float4(fmaf(acc[4], dnode, b1.x), fmaf(acc[5], dnode, b1.y),
                                 fmaf(acc[6], dnode, b1.z), fmaf(acc[7], dnode, b1.w));
}

extern "C" void kernel_launch(void* const* d_in, const int* in_sizes, int n_in,
                              void* d_out, int out_size, void* d_ws, size_t ws_size,
                              hipStream_t stream) {
  const float* x  = (const float*)d_in[0];
  const int*   ei = (const int*)d_in[1];
  const float* W1 = (const float*)d_in[2];
  const float* b1 = (const float*)d_in[3];
  const float* W2 = (const float*)d_in[4];
  const float* b2 = (const float*)d_in[5];
  float* out = (float*)d_out;

  const int N = in_sizes[0] / IN_C;             // 50000
  const int E = in_sizes[1] / 2;                // 800000
  const int K = (N + BKT_NODES - 1) >> BKT_SH;  // 196 buckets
  const int NTILES = (N + 15) / 16;             // 3125
  const int P1B = (E + CHUNK - 1) / CHUNK;      // 196
  const int GB1 = (NTILES + 3) / 4;             // 782

  char* ws = (char*)d_ws;
  size_t off = 0;
  auto alloc = [&](size_t bytes) -> void* {
    void* p = ws + off;
    off += (bytes + 255) & ~(size_t)255;
    return p;
  };
  int* bcnt    = (int*)alloc((size_t)K * 4);
  int* ovf_cnt = (int*)alloc(4);
  int* ovfb    = (int*)alloc((size_t)K * 4);
  size_t zero_bytes = off;
  const int zints = (int)(zero_bytes / 4);

  int*   rowstart    = (int*)  alloc((size_t)(N + 1) * 4);
  float* dinv        = (float*)alloc((size_t)N * 4);
  unsigned* pairs    = (unsigned*)alloc((size_t)K * CAPB * 4);
  uint2* ovf         = (uint2*)alloc((size_t)OVF_CAP * 8);
  unsigned short* csr = (unsigned short*)alloc((size_t)E * 2);
  unsigned short* hs  = (unsigned short*)alloc((size_t)N * HID_C * 2);
  unsigned short* hs2 = (unsigned short*)alloc((size_t)N * OUT_C * 2);
  short* w1t         = (short*)alloc((size_t)IN_C * HID_C * 2);
  short* w2t         = (short*)alloc((size_t)HID_C * OUT_C * 2);

  int wt_threads = zints > IN_C * HID_C ? zints : IN_C * HID_C;
  wt_zero_kernel<<<(wt_threads + 255) / 256, 256, 0, stream>>>(
      W1, W2, w1t, w2t, (int*)ws, zints);

  p1_gemm1_kernel<<<P1B + GB1, 256, 0, stream>>>(
      ei, pairs, bcnt, ovf, ovf_cnt, ovfb, E, K, P1B, x, w1t, hs, NTILES);

  phase2_csr_kernel<<<K, 256, 0, stream>>>(
      pairs, bcnt, ovfb, ovf, ovf_cnt, rowstart, dinv, csr, N, K);

  agg1_gemm2_kernel<<<NTILES, 256, 0, stream>>>(
      hs, rowstart, csr, dinv, b1, w2t, hs2, N);

  agg2_kernel<<<(N + 31) / 32, 256, 0, stream>>>(
      hs2, rowstart, csr, dinv, b2, out, N);
}